// Round 11
// baseline (382.576 us; speedup 1.0000x reference)
//
#include <hip/hip_runtime.h>

#define EMB 128
#define N_ITEMS 50000
#define N_SESS 50000
#define N_TOTAL 100000
#define NNZ_S 500000
#define NNZ_A 3200000
#define BATCH 2048
#define N_SCORE 50000

#define RPB 64                                 // rows per bucket
#define NB_A ((N_TOTAL + RPB - 1) / RPB)       // 1563
#define NB_S ((N_SESS + RPB - 1) / RPB)        // 782
#define NBMAX 1600
#define EPT 8
#define EPB (256 * EPT)                        // 2048 edges per build block
#define NBLK_S ((NNZ_S + EPB - 1) / EPB)       // 245
#define NBLK_A ((NNZ_A + EPB - 1) / EPB)       // 1563
#define XW_BLKS ((N_ITEMS + 127) / 128)        // 391
#define CHUNK 4096                             // edges staged per sort pass

#define STRIDE_S 1024                          // slots per S bucket (mean 640, sd 25)
#define STRIDE_A 2560                          // slots per A bucket (mean 2048, sd 45; filtered ~41%)

#define MARK_BLKS ((BATCH + N_SCORE + 255) / 256)  // 204

#define SB_X ((N_SCORE + 127) / 128)           // 391
#define SB_Y (BATCH / 256)                     // 8
#define SB_TOT (SB_X * SB_Y)                   // 3128 = 8 * 391

typedef __attribute__((ext_vector_type(8))) short bf16x8;
typedef __attribute__((ext_vector_type(4))) float f32x4;

__device__ inline ushort f2bf(float f) {
    unsigned u = __float_as_uint(f);
    unsigned r = (u + 0x7fff + ((u >> 16) & 1)) >> 16;
    return (ushort)r;
}
__device__ inline float bflo(unsigned u) { return __uint_as_float(u << 16); }
__device__ inline float bfhi(unsigned u) { return __uint_as_float(u & 0xffff0000u); }

// ---------------- PREP: mark needed h1 rows + W transpose ----------------
__global__ __launch_bounds__(256) void k_prep(const int* __restrict__ bidx, const int* __restrict__ iidx,
                                              unsigned* __restrict__ bm,
                                              const float* __restrict__ W, ushort* __restrict__ Wt) {
    int blk = blockIdx.x;
    int tid = threadIdx.x;
    if (blk < MARK_BLKS) {
        int i = blk * 256 + tid;
        int r = -1;
        if (i < BATCH) r = bidx[i];
        else if (i < BATCH + N_SCORE) r = iidx[i - BATCH];
        if (r >= 0) atomicOr(&bm[r >> 5], 1u << (r & 31));
    } else {
        int i = (blk - MARK_BLKS) * 256 + tid;
        int n = i >> 7, k = i & 127;
        Wt[n * 128 + k] = f2bf(W[k * 128 + n]);
    }
}

// ---------------- BUILD: strided bucketed placement (S + A-filtered) + fused-gather xw GEMM ----------------
// edge packed: key = (row & 63) << 17 | col, val as int bits
__global__ __launch_bounds__(256) void k_build(const int* __restrict__ sRows, const int* __restrict__ sCols,
                                               const float* __restrict__ sVals, int* __restrict__ tailS,
                                               int2* __restrict__ edgS,
                                               const int* __restrict__ aRows, const int* __restrict__ aCols,
                                               const float* __restrict__ aVals, int* __restrict__ tailA,
                                               int2* __restrict__ edgA,
                                               const unsigned* __restrict__ bm,
                                               const float* __restrict__ emb,
                                               const int* __restrict__ emb_idx,
                                               const ushort* __restrict__ Wt,
                                               ushort* __restrict__ xw_item) {
    __shared__ int h[NBMAX];
    __shared__ int base_s[NBMAX];
    int blk = blockIdx.x;
    int tid = threadIdx.x;
    if (blk < NBLK_S + NBLK_A) {
        // ---- placement (strided regions, no scan needed) ----
        const int *rows, *cols;
        const float* vals;
        int* tail;
        int2* out;
        const unsigned* filt;
        int nnz, nb, stride;
        long b0;
        if (blk < NBLK_S) {
            rows = sRows; cols = sCols; vals = sVals; tail = tailS; out = edgS;
            filt = nullptr; nnz = NNZ_S; nb = NB_S; stride = STRIDE_S;
            b0 = (long)blk * EPB;
        } else {
            rows = aRows; cols = aCols; vals = aVals; tail = tailA; out = edgA;
            filt = bm; nnz = NNZ_A; nb = NB_A; stride = STRIDE_A;
            b0 = (long)(blk - NBLK_S) * EPB;
        }
        for (int i = tid; i < nb; i += 256) h[i] = 0;
        __syncthreads();
        int er[EPT], ec[EPT];
        float ev[EPT];
#pragma unroll
        for (int j = 0; j < EPT; ++j) {
            long e = b0 + j * 256 + tid;
            er[j] = -1;
            if (e < nnz) {
                int r = rows[e];
                if (!filt || ((filt[r >> 5] >> (r & 31)) & 1)) {
                    er[j] = r;
                    ec[j] = cols[e];
                    ev[j] = vals[e];
                    atomicAdd(&h[r >> 6], 1);
                }
            }
        }
        __syncthreads();
        for (int i = tid; i < nb; i += 256) {
            int v = h[i];
            if (v) base_s[i] = atomicAdd(&tail[i], v);
            h[i] = 0; // reuse as local cursor
        }
        __syncthreads();
#pragma unroll
        for (int j = 0; j < EPT; ++j) {
            if (er[j] >= 0) {
                int bk = er[j] >> 6;
                int loc = base_s[bk] + atomicAdd(&h[bk], 1);
                if (loc < stride) // paranoia clamp (prob ~0; keeps writes in-buffer)
                    out[(long)bk * stride + loc] = make_int2(((er[j] & 63) << 17) | ec[j],
                                                             __float_as_int(ev[j]));
            }
        }
    } else {
        // ---- xw_item = bf16(emb[emb_idx]) @ Wt^T via MFMA (fused gather, swapped operands) ----
        int bid = blk - NBLK_S - NBLK_A;
        int wid = tid >> 6;
        int lane = tid & 63;
        int wm = wid >> 1, wn = wid & 1;
        long m0 = (long)bid * 128 + wm * 64;
        int n0 = wn * 64;
        int r = lane & 15;
        int kg = lane >> 4;

        long arow[4];
#pragma unroll
        for (int mf = 0; mf < 4; ++mf) {
            long row = m0 + mf * 16 + r;
            if (row >= N_ITEMS) row = N_ITEMS - 1; // clamp, stores guarded
            arow[mf] = emb_idx[row];
        }

        f32x4 acc[4][4] = {};
#pragma unroll
        for (int ks = 0; ks < 4; ++ks) {
            bf16x8 a[4], b[4];
#pragma unroll
            for (int mf = 0; mf < 4; ++mf) {
                const float* p = emb + arow[mf] * EMB + ks * 32 + kg * 8;
                float4 lo = *(const float4*)p;
                float4 hi = *(const float4*)(p + 4);
                bf16x8 t;
                t[0] = (short)f2bf(lo.x); t[1] = (short)f2bf(lo.y);
                t[2] = (short)f2bf(lo.z); t[3] = (short)f2bf(lo.w);
                t[4] = (short)f2bf(hi.x); t[5] = (short)f2bf(hi.y);
                t[6] = (short)f2bf(hi.z); t[7] = (short)f2bf(hi.w);
                a[mf] = t;
            }
#pragma unroll
            for (int nf = 0; nf < 4; ++nf) {
                int row = n0 + nf * 16 + r;
                b[nf] = *(const bf16x8*)(Wt + (long)row * EMB + ks * 32 + kg * 8);
            }
            // swapped: acc = D^T -> lane holds row (m) = r, 4 consecutive cols (n) = kg*4+j
#pragma unroll
            for (int mf = 0; mf < 4; ++mf)
#pragma unroll
                for (int nf = 0; nf < 4; ++nf)
                    acc[mf][nf] = __builtin_amdgcn_mfma_f32_16x16x32_bf16(b[nf], a[mf], acc[mf][nf], 0, 0, 0);
        }
#pragma unroll
        for (int mf = 0; mf < 4; ++mf) {
            long row = m0 + mf * 16 + r;
            if (row < N_ITEMS) {
#pragma unroll
                for (int nf = 0; nf < 4; ++nf) {
                    int col0 = n0 + nf * 16 + kg * 4;
                    ushort4 o;
                    o.x = f2bf(acc[mf][nf][0]);
                    o.y = f2bf(acc[mf][nf][1]);
                    o.z = f2bf(acc[mf][nf][2]);
                    o.w = f2bf(acc[mf][nf][3]);
                    *(ushort4*)(xw_item + row * EMB + col0) = o;
                }
            }
        }
    }
}

// ---------------- sorted-bucket SpMM over strided edge regions ----------------
// 2 edges per wave step: half-wave h processes edge e+h, lane covers 4 dims (uint2);
// cross-half shfl_xor(32) reduction at the end.
__global__ __launch_bounds__(512) void k_spmm_sorted(const int* __restrict__ tail,
                                                     const int2* __restrict__ edges, int stride,
                                                     const ushort* __restrict__ src,
                                                     ushort* __restrict__ dst,
                                                     const float* __restrict__ bias,
                                                     int nrows,
                                                     const unsigned* __restrict__ bm) {
    __shared__ int2 se[CHUNK];      // 32 KB sorted edge buffer
    __shared__ int hist[RPB], sofs[RPB], cur[RPB];
    int tid = threadIdx.x, lane = tid & 63, w = tid >> 6;
    int half = lane >> 5, l32 = lane & 31;
    int bk = blockIdx.x;
    long begin = (long)bk * stride;
    int cnt = tail[bk];
    if (cnt > stride) cnt = stride;
    long end = begin + cnt;

    float4 acc[8] = {};
    for (long cbase = begin; cbase < end; cbase += CHUNK) {
        int m = (int)(end - cbase);
        if (m > CHUNK) m = CHUNK;
        if (tid < RPB) hist[tid] = 0;
        __syncthreads();
        int2 er[CHUNK / 512];
#pragma unroll
        for (int j = 0; j < CHUNK / 512; ++j) {
            int idx = j * 512 + tid;
            if (idx < m) {
                er[j] = edges[cbase + idx];
                atomicAdd(&hist[er[j].x >> 17], 1);
            } else {
                er[j].x = -1;
            }
        }
        __syncthreads();
        if (w == 0) {
            int v = hist[lane];
            int x = v;
#pragma unroll
            for (int s = 1; s < 64; s <<= 1) {
                int t = __shfl_up(x, s, 64);
                if (lane >= s) x += t;
            }
            sofs[lane] = x - v;
            cur[lane] = x - v;
        }
        __syncthreads();
#pragma unroll
        for (int j = 0; j < CHUNK / 512; ++j) {
            if (er[j].x >= 0) {
                int lr = er[j].x >> 17;
                int p = atomicAdd(&cur[lr], 1);
                se[p] = er[j];
            }
        }
        __syncthreads();
#pragma unroll
        for (int i = 0; i < 8; ++i) {
            int lr = w * 8 + i;
            int e = sofs[lr];
            int s1 = e + hist[lr];
            for (; e + 4 <= s1; e += 4) {
                int2 ea = se[e + half];
                int2 eb = se[e + 2 + half];
                uint2 ua = *(const uint2*)(src + (long)(ea.x & 0x1FFFF) * EMB + l32 * 4);
                uint2 ub = *(const uint2*)(src + (long)(eb.x & 0x1FFFF) * EMB + l32 * 4);
                float va = __int_as_float(ea.y), vb = __int_as_float(eb.y);
                acc[i].x += va * bflo(ua.x) + vb * bflo(ub.x);
                acc[i].y += va * bfhi(ua.x) + vb * bfhi(ub.x);
                acc[i].z += va * bflo(ua.y) + vb * bflo(ub.y);
                acc[i].w += va * bfhi(ua.y) + vb * bfhi(ub.y);
            }
            for (; e < s1; e += 2) {
                int eh = e + half;
                if (eh < s1) {
                    int2 e0 = se[eh];
                    uint2 u0 = *(const uint2*)(src + (long)(e0.x & 0x1FFFF) * EMB + l32 * 4);
                    float v0 = __int_as_float(e0.y);
                    acc[i].x += v0 * bflo(u0.x);
                    acc[i].y += v0 * bfhi(u0.x);
                    acc[i].z += v0 * bflo(u0.y);
                    acc[i].w += v0 * bfhi(u0.y);
                }
            }
        }
        __syncthreads();
    }
#pragma unroll
    for (int i = 0; i < 8; ++i) {
        int r = bk * RPB + w * 8 + i;
        if (r < nrows && (!bm || ((bm[r >> 5] >> (r & 31)) & 1))) {
            float4 t = acc[i];
            t.x += __shfl_xor(t.x, 32, 64);
            t.y += __shfl_xor(t.y, 32, 64);
            t.z += __shfl_xor(t.z, 32, 64);
            t.w += __shfl_xor(t.w, 32, 64);
            if (half == 0) {
                if (bias) {
                    float4 bb = *(const float4*)(bias + l32 * 4);
                    t.x += bb.x; t.y += bb.y; t.z += bb.z; t.w += bb.w;
                }
                uint2 o;
                o.x = (unsigned)f2bf(t.x) | ((unsigned)f2bf(t.y) << 16);
                o.y = (unsigned)f2bf(t.z) | ((unsigned)f2bf(t.w) << 16);
                *(uint2*)(dst + (long)r * EMB + l32 * 4) = o;
            }
        }
    }
}

// ---------------- out[2048, 50000] = h1[bidx] @ h1[iidx]^T via MFMA (inline gather) ----------------
// 512 threads, 256x128 tile, swapped-operand MFMA -> float4 nontemporal stores.
__global__ __launch_bounds__(512) void k_score_mfma(const ushort* __restrict__ H,
                                                    const int* __restrict__ bidx,
                                                    const int* __restrict__ iidx,
                                                    float* __restrict__ C) {
    const int q = SB_TOT / 8; // 391, exact
    int bid = blockIdx.x;
    int nb = (bid % 8) * q + bid / 8;   // bijective chunked swizzle
    int bx = nb / SB_Y;                 // consecutive nb share bx (same hi slice)
    int by = nb % SB_Y;

    int wid = threadIdx.x >> 6;
    int lane = threadIdx.x & 63;
    int wm = wid >> 1, wn = wid & 1;    // wm 0..3, wn 0..1
    long m0 = (long)by * 256 + wm * 64;
    long n0 = (long)bx * 128 + wn * 64;
    int r = lane & 15;
    int kg = lane >> 4;

    long arow[4], brow[4];
#pragma unroll
    for (int mf = 0; mf < 4; ++mf) arow[mf] = bidx[m0 + mf * 16 + r];
#pragma unroll
    for (int nf = 0; nf < 4; ++nf) {
        long row = n0 + nf * 16 + r;
        if (row >= N_SCORE) row = N_SCORE - 1; // clamp: safe load, stores guarded
        brow[nf] = iidx[row];
    }

    f32x4 acc[4][4] = {};
#pragma unroll
    for (int ks = 0; ks < 4; ++ks) {
        bf16x8 a[4], b[4];
#pragma unroll
        for (int mf = 0; mf < 4; ++mf)
            a[mf] = *(const bf16x8*)(H + arow[mf] * EMB + ks * 32 + kg * 8);
#pragma unroll
        for (int nf = 0; nf < 4; ++nf)
            b[nf] = *(const bf16x8*)(H + brow[nf] * EMB + ks * 32 + kg * 8);
        // swapped: acc = D^T -> lane holds output row m = m0+mf*16+r, cols n = n0+nf*16+kg*4+j
#pragma unroll
        for (int mf = 0; mf < 4; ++mf)
#pragma unroll
            for (int nf = 0; nf < 4; ++nf)
                acc[mf][nf] = __builtin_amdgcn_mfma_f32_16x16x32_bf16(b[nf], a[mf], acc[mf][nf], 0, 0, 0);
    }
#pragma unroll
    for (int mf = 0; mf < 4; ++mf) {
        long row = m0 + mf * 16 + r;
#pragma unroll
        for (int nf = 0; nf < 4; ++nf) {
            long col0 = n0 + nf * 16 + kg * 4;
            if (col0 < N_SCORE) { // N_SCORE % 4 == 0 -> full float4 in-bounds
                f32x4* p = (f32x4*)&C[row * N_SCORE + col0];
                __builtin_nontemporal_store(acc[mf][nf], p);
            }
        }
    }
}

extern "C" void kernel_launch(void* const* d_in, const int* in_sizes, int n_in,
                              void* d_out, int out_size, void* d_ws, size_t ws_size,
                              hipStream_t stream) {
    const float* emb_table      = (const float*)d_in[0];
    const float* W              = (const float*)d_in[1];
    const float* b              = (const float*)d_in[2];
    const float* sess_vals      = (const float*)d_in[3];
    const float* A_vals         = (const float*)d_in[4];
    const int*   batch_idxes    = (const int*)d_in[5];
    const int*   item_idxes     = (const int*)d_in[6];
    const int*   item_emb_idxes = (const int*)d_in[7];
    const int*   sess_rows      = (const int*)d_in[8];
    const int*   sess_cols      = (const int*)d_in[9];
    const int*   A_rows         = (const int*)d_in[10];
    const int*   A_cols         = (const int*)d_in[11];
    float* out = (float*)d_out;

    // -------- workspace layout (bytes), ~90 MB --------
    char* base = (char*)d_ws;
    ushort*   xw    = (ushort*)(base + 0);            // [N_TOTAL,128] bf16, 25.6MB
    ushort*   h1    = (ushort*)(base + 25600000L);    // [N_TOTAL,128] bf16, 25.6MB
    int2*     edgA  = (int2*)  (base + 51200000L);    // NB_A x STRIDE_A x 8B = 32.0MB
    int2*     edgS  = (int2*)  (base + 83210240L);    // NB_S x STRIDE_S x 8B = 6.4MB
    ushort*   Wt    = (ushort*)(base + 89616384L);    // 128x128 bf16, 32KB
    // zeroed-together region: bm | tailS | tailA
    unsigned* bm    = (unsigned*)(base + 89649152L);  // 3136 words
    int*      tailS = (int*)   (base + 89661696L);    // NB_S
    int*      tailA = (int*)   (base + 89664824L);    // NB_A

    ushort* xw_item = xw + (long)N_SESS * EMB;  // item half of xw

    // ---- zero bm + tails in one memset ----
    hipMemsetAsync(bm, 0, 89671076L - 89649152L, stream);
    // ---- PREP: mark needed h1 rows + convW ----
    k_prep<<<MARK_BLKS + 64, 256, 0, stream>>>(batch_idxes, item_idxes, bm, W, Wt);
    // ---- BUILD: strided placement (S, A-filtered) + fused-gather xw GEMM ----
    k_build<<<NBLK_S + NBLK_A + XW_BLKS, 256, 0, stream>>>(
        sess_rows, sess_cols, sess_vals, tailS, edgS,
        A_rows, A_cols, A_vals, tailA, edgA, bm,
        emb_table, item_emb_idxes, Wt, xw_item);
    // ---- spmm1 (reordered): xw[0:N_SESS] = S @ xw_item ----
    k_spmm_sorted<<<NB_S, 512, 0, stream>>>(tailS, edgS, STRIDE_S, xw_item, xw,
                                            nullptr, N_SESS, nullptr);
    // ---- spmm2 + fused bias -> h1 (only needed rows written) ----
    k_spmm_sorted<<<NB_A, 512, 0, stream>>>(tailA, edgA, STRIDE_A, xw, h1,
                                            b, N_TOTAL, bm);
    // ---- score (1D grid, XCD-swizzled, inline hb/hi gather, float4 NT stores) ----
    k_score_mfma<<<SB_TOT, 512, 0, stream>>>(h1, batch_idxes, item_idxes, out);
}

// Round 12
// 374.561 us; speedup vs baseline: 1.0214x; 1.0214x over previous
//
#include <hip/hip_runtime.h>

#define EMB 128
#define N_ITEMS 50000
#define N_SESS 50000
#define N_TOTAL 100000
#define NNZ_S 500000
#define NNZ_A 3200000
#define BATCH 2048
#define N_SCORE 50000

#define RPB 64                                 // rows per bucket
#define NB_A ((N_TOTAL + RPB - 1) / RPB)       // 1563
#define NB_S ((N_SESS + RPB - 1) / RPB)        // 782
#define NBMAX 1600
#define EPT 8
#define EPB (256 * EPT)                        // 2048 edges per build block
#define NBLK_S ((NNZ_S + EPB - 1) / EPB)       // 245
#define NBLK_A ((NNZ_A + EPB - 1) / EPB)       // 1563
#define XW_BLKS ((N_ITEMS + 127) / 128)        // 391
#define CHUNK 4096                             // edges staged per sort pass

#define STRIDE_S 1024                          // slots per S bucket (mean 640, sd 25)
#define STRIDE_A 2560                          // slots per A bucket (mean 2048, sd 45; filtered ~41%)

#define MARK_BLKS ((BATCH + N_SCORE + 255) / 256)  // 204

#define SB_X ((N_SCORE + 127) / 128)           // 391
#define SB_Y (BATCH / 256)                     // 8
#define SB_TOT (SB_X * SB_Y)                   // 3128 = 8 * 391

typedef __attribute__((ext_vector_type(8))) short bf16x8;
typedef __attribute__((ext_vector_type(4))) float f32x4;

__device__ inline ushort f2bf(float f) {
    unsigned u = __float_as_uint(f);
    unsigned r = (u + 0x7fff + ((u >> 16) & 1)) >> 16;
    return (ushort)r;
}
__device__ inline float bflo(unsigned u) { return __uint_as_float(u << 16); }
__device__ inline float bfhi(unsigned u) { return __uint_as_float(u & 0xffff0000u); }

// ---------------- PREP: mark needed h1 rows + W transpose ----------------
__global__ __launch_bounds__(256) void k_prep(const int* __restrict__ bidx, const int* __restrict__ iidx,
                                              unsigned* __restrict__ bm,
                                              const float* __restrict__ W, ushort* __restrict__ Wt) {
    int blk = blockIdx.x;
    int tid = threadIdx.x;
    if (blk < MARK_BLKS) {
        int i = blk * 256 + tid;
        int r = -1;
        if (i < BATCH) r = bidx[i];
        else if (i < BATCH + N_SCORE) r = iidx[i - BATCH];
        if (r >= 0) atomicOr(&bm[r >> 5], 1u << (r & 31));
    } else {
        int i = (blk - MARK_BLKS) * 256 + tid;
        int n = i >> 7, k = i & 127;
        Wt[n * 128 + k] = f2bf(W[k * 128 + n]);
    }
}

// ---------------- BUILD: strided bucketed placement (S + A-filtered) + fused-gather xw GEMM ----------------
// edge packed: key = (row & 63) << 17 | col, val as int bits
__global__ __launch_bounds__(256) void k_build(const int* __restrict__ sRows, const int* __restrict__ sCols,
                                               const float* __restrict__ sVals, int* __restrict__ tailS,
                                               int2* __restrict__ edgS,
                                               const int* __restrict__ aRows, const int* __restrict__ aCols,
                                               const float* __restrict__ aVals, int* __restrict__ tailA,
                                               int2* __restrict__ edgA,
                                               const unsigned* __restrict__ bm,
                                               const float* __restrict__ emb,
                                               const int* __restrict__ emb_idx,
                                               const ushort* __restrict__ Wt,
                                               ushort* __restrict__ xw_item) {
    __shared__ int h[NBMAX];
    __shared__ int base_s[NBMAX];
    int blk = blockIdx.x;
    int tid = threadIdx.x;
    if (blk < NBLK_S + NBLK_A) {
        // ---- placement (strided regions, no scan needed) ----
        const int *rows, *cols;
        const float* vals;
        int* tail;
        int2* out;
        const unsigned* filt;
        int nnz, nb, stride;
        long b0;
        if (blk < NBLK_S) {
            rows = sRows; cols = sCols; vals = sVals; tail = tailS; out = edgS;
            filt = nullptr; nnz = NNZ_S; nb = NB_S; stride = STRIDE_S;
            b0 = (long)blk * EPB;
        } else {
            rows = aRows; cols = aCols; vals = aVals; tail = tailA; out = edgA;
            filt = bm; nnz = NNZ_A; nb = NB_A; stride = STRIDE_A;
            b0 = (long)(blk - NBLK_S) * EPB;
        }
        for (int i = tid; i < nb; i += 256) h[i] = 0;
        __syncthreads();
        int er[EPT], ec[EPT];
        float ev[EPT];
#pragma unroll
        for (int j = 0; j < EPT; ++j) {
            long e = b0 + j * 256 + tid;
            er[j] = -1;
            if (e < nnz) {
                int r = rows[e];
                if (!filt || ((filt[r >> 5] >> (r & 31)) & 1)) {
                    er[j] = r;
                    ec[j] = cols[e];
                    ev[j] = vals[e];
                    atomicAdd(&h[r >> 6], 1);
                }
            }
        }
        __syncthreads();
        for (int i = tid; i < nb; i += 256) {
            int v = h[i];
            if (v) base_s[i] = atomicAdd(&tail[i], v);
            h[i] = 0; // reuse as local cursor
        }
        __syncthreads();
#pragma unroll
        for (int j = 0; j < EPT; ++j) {
            if (er[j] >= 0) {
                int bk = er[j] >> 6;
                int loc = base_s[bk] + atomicAdd(&h[bk], 1);
                if (loc < stride) // paranoia clamp (prob ~0; keeps writes in-buffer)
                    out[(long)bk * stride + loc] = make_int2(((er[j] & 63) << 17) | ec[j],
                                                             __float_as_int(ev[j]));
            }
        }
    } else {
        // ---- xw_item = bf16(emb[emb_idx]) @ Wt^T via MFMA (fused gather, swapped operands) ----
        int bid = blk - NBLK_S - NBLK_A;
        int wid = tid >> 6;
        int lane = tid & 63;
        int wm = wid >> 1, wn = wid & 1;
        long m0 = (long)bid * 128 + wm * 64;
        int n0 = wn * 64;
        int r = lane & 15;
        int kg = lane >> 4;

        long arow[4];
#pragma unroll
        for (int mf = 0; mf < 4; ++mf) {
            long row = m0 + mf * 16 + r;
            if (row >= N_ITEMS) row = N_ITEMS - 1; // clamp, stores guarded
            arow[mf] = emb_idx[row];
        }

        f32x4 acc[4][4] = {};
#pragma unroll
        for (int ks = 0; ks < 4; ++ks) {
            bf16x8 a[4], b[4];
#pragma unroll
            for (int mf = 0; mf < 4; ++mf) {
                const float* p = emb + arow[mf] * EMB + ks * 32 + kg * 8;
                float4 lo = *(const float4*)p;
                float4 hi = *(const float4*)(p + 4);
                bf16x8 t;
                t[0] = (short)f2bf(lo.x); t[1] = (short)f2bf(lo.y);
                t[2] = (short)f2bf(lo.z); t[3] = (short)f2bf(lo.w);
                t[4] = (short)f2bf(hi.x); t[5] = (short)f2bf(hi.y);
                t[6] = (short)f2bf(hi.z); t[7] = (short)f2bf(hi.w);
                a[mf] = t;
            }
#pragma unroll
            for (int nf = 0; nf < 4; ++nf) {
                int row = n0 + nf * 16 + r;
                b[nf] = *(const bf16x8*)(Wt + (long)row * EMB + ks * 32 + kg * 8);
            }
            // swapped: acc = D^T -> lane holds row (m) = r, 4 consecutive cols (n) = kg*4+j
#pragma unroll
            for (int mf = 0; mf < 4; ++mf)
#pragma unroll
                for (int nf = 0; nf < 4; ++nf)
                    acc[mf][nf] = __builtin_amdgcn_mfma_f32_16x16x32_bf16(b[nf], a[mf], acc[mf][nf], 0, 0, 0);
        }
#pragma unroll
        for (int mf = 0; mf < 4; ++mf) {
            long row = m0 + mf * 16 + r;
            if (row < N_ITEMS) {
#pragma unroll
                for (int nf = 0; nf < 4; ++nf) {
                    int col0 = n0 + nf * 16 + kg * 4;
                    ushort4 o;
                    o.x = f2bf(acc[mf][nf][0]);
                    o.y = f2bf(acc[mf][nf][1]);
                    o.z = f2bf(acc[mf][nf][2]);
                    o.w = f2bf(acc[mf][nf][3]);
                    *(ushort4*)(xw_item + row * EMB + col0) = o;
                }
            }
        }
    }
}

// ---------------- sorted-bucket SpMM over strided edge regions (round-9 proven version) ----------------
__global__ __launch_bounds__(512) void k_spmm_sorted(const int* __restrict__ tail,
                                                     const int2* __restrict__ edges, int stride,
                                                     const ushort* __restrict__ src,
                                                     ushort* __restrict__ dst,
                                                     const float* __restrict__ bias,
                                                     int nrows,
                                                     const unsigned* __restrict__ bm) {
    __shared__ int2 se[CHUNK];      // 32 KB sorted edge buffer
    __shared__ int hist[RPB], sofs[RPB], cur[RPB];
    int tid = threadIdx.x, lane = tid & 63, w = tid >> 6;
    int bk = blockIdx.x;
    long begin = (long)bk * stride;
    int cnt = tail[bk];
    if (cnt > stride) cnt = stride;
    long end = begin + cnt;

    float2 acc[8] = {};
    for (long cbase = begin; cbase < end; cbase += CHUNK) {
        int m = (int)(end - cbase);
        if (m > CHUNK) m = CHUNK;
        if (tid < RPB) hist[tid] = 0;
        __syncthreads();
        int2 er[CHUNK / 512];
#pragma unroll
        for (int j = 0; j < CHUNK / 512; ++j) {
            int idx = j * 512 + tid;
            if (idx < m) {
                er[j] = edges[cbase + idx];
                atomicAdd(&hist[er[j].x >> 17], 1);
            } else {
                er[j].x = -1;
            }
        }
        __syncthreads();
        if (w == 0) {
            int v = hist[lane];
            int x = v;
#pragma unroll
            for (int s = 1; s < 64; s <<= 1) {
                int t = __shfl_up(x, s, 64);
                if (lane >= s) x += t;
            }
            sofs[lane] = x - v;
            cur[lane] = x - v;
        }
        __syncthreads();
#pragma unroll
        for (int j = 0; j < CHUNK / 512; ++j) {
            if (er[j].x >= 0) {
                int lr = er[j].x >> 17;
                int p = atomicAdd(&cur[lr], 1);
                se[p] = er[j];
            }
        }
        __syncthreads();
#pragma unroll
        for (int i = 0; i < 8; ++i) {
            int lr = w * 8 + i;
            int e = sofs[lr];
            int s1 = e + hist[lr];
            for (; e + 4 <= s1; e += 4) {
                int2 e0 = se[e], e1 = se[e + 1], e2 = se[e + 2], e3 = se[e + 3];
                unsigned u0 = *(const unsigned*)(src + (long)(e0.x & 0x1FFFF) * EMB + lane * 2);
                unsigned u1 = *(const unsigned*)(src + (long)(e1.x & 0x1FFFF) * EMB + lane * 2);
                unsigned u2 = *(const unsigned*)(src + (long)(e2.x & 0x1FFFF) * EMB + lane * 2);
                unsigned u3 = *(const unsigned*)(src + (long)(e3.x & 0x1FFFF) * EMB + lane * 2);
                float v0 = __int_as_float(e0.y), v1 = __int_as_float(e1.y);
                float v2 = __int_as_float(e2.y), v3 = __int_as_float(e3.y);
                acc[i].x += v0 * bflo(u0) + v1 * bflo(u1) + v2 * bflo(u2) + v3 * bflo(u3);
                acc[i].y += v0 * bfhi(u0) + v1 * bfhi(u1) + v2 * bfhi(u2) + v3 * bfhi(u3);
            }
            for (; e < s1; ++e) {
                int2 e0 = se[e];
                unsigned u0 = *(const unsigned*)(src + (long)(e0.x & 0x1FFFF) * EMB + lane * 2);
                float v0 = __int_as_float(e0.y);
                acc[i].x += v0 * bflo(u0);
                acc[i].y += v0 * bfhi(u0);
            }
        }
        __syncthreads();
    }
#pragma unroll
    for (int i = 0; i < 8; ++i) {
        int r = bk * RPB + w * 8 + i;
        if (r < nrows && (!bm || ((bm[r >> 5] >> (r & 31)) & 1))) {
            float a = acc[i].x, c = acc[i].y;
            if (bias) {
                a += bias[lane * 2];
                c += bias[lane * 2 + 1];
            }
            unsigned o = (unsigned)f2bf(a) | ((unsigned)f2bf(c) << 16);
            *((unsigned*)(dst + (long)r * EMB) + lane) = o;
        }
    }
}

// ---------------- out[2048, 50000] = h1[bidx] @ h1[iidx]^T via MFMA (inline gather) ----------------
// 512 threads, 256x128 tile, swapped-operand MFMA -> float4 nontemporal stores.
__global__ __launch_bounds__(512) void k_score_mfma(const ushort* __restrict__ H,
                                                    const int* __restrict__ bidx,
                                                    const int* __restrict__ iidx,
                                                    float* __restrict__ C) {
    const int q = SB_TOT / 8; // 391, exact
    int bid = blockIdx.x;
    int nb = (bid % 8) * q + bid / 8;   // bijective chunked swizzle
    int bx = nb / SB_Y;                 // consecutive nb share bx (same hi slice)
    int by = nb % SB_Y;

    int wid = threadIdx.x >> 6;
    int lane = threadIdx.x & 63;
    int wm = wid >> 1, wn = wid & 1;    // wm 0..3, wn 0..1
    long m0 = (long)by * 256 + wm * 64;
    long n0 = (long)bx * 128 + wn * 64;
    int r = lane & 15;
    int kg = lane >> 4;

    long arow[4], brow[4];
#pragma unroll
    for (int mf = 0; mf < 4; ++mf) arow[mf] = bidx[m0 + mf * 16 + r];
#pragma unroll
    for (int nf = 0; nf < 4; ++nf) {
        long row = n0 + nf * 16 + r;
        if (row >= N_SCORE) row = N_SCORE - 1; // clamp: safe load, stores guarded
        brow[nf] = iidx[row];
    }

    f32x4 acc[4][4] = {};
#pragma unroll
    for (int ks = 0; ks < 4; ++ks) {
        bf16x8 a[4], b[4];
#pragma unroll
        for (int mf = 0; mf < 4; ++mf)
            a[mf] = *(const bf16x8*)(H + arow[mf] * EMB + ks * 32 + kg * 8);
#pragma unroll
        for (int nf = 0; nf < 4; ++nf)
            b[nf] = *(const bf16x8*)(H + brow[nf] * EMB + ks * 32 + kg * 8);
        // swapped: acc = D^T -> lane holds output row m = m0+mf*16+r, cols n = n0+nf*16+kg*4+j
#pragma unroll
        for (int mf = 0; mf < 4; ++mf)
#pragma unroll
            for (int nf = 0; nf < 4; ++nf)
                acc[mf][nf] = __builtin_amdgcn_mfma_f32_16x16x32_bf16(b[nf], a[mf], acc[mf][nf], 0, 0, 0);
    }
#pragma unroll
    for (int mf = 0; mf < 4; ++mf) {
        long row = m0 + mf * 16 + r;
#pragma unroll
        for (int nf = 0; nf < 4; ++nf) {
            long col0 = n0 + nf * 16 + kg * 4;
            if (col0 < N_SCORE) { // N_SCORE % 4 == 0 -> full float4 in-bounds
                f32x4* p = (f32x4*)&C[row * N_SCORE + col0];
                __builtin_nontemporal_store(acc[mf][nf], p);
            }
        }
    }
}

extern "C" void kernel_launch(void* const* d_in, const int* in_sizes, int n_in,
                              void* d_out, int out_size, void* d_ws, size_t ws_size,
                              hipStream_t stream) {
    const float* emb_table      = (const float*)d_in[0];
    const float* W              = (const float*)d_in[1];
    const float* b              = (const float*)d_in[2];
    const float* sess_vals      = (const float*)d_in[3];
    const float* A_vals         = (const float*)d_in[4];
    const int*   batch_idxes    = (const int*)d_in[5];
    const int*   item_idxes     = (const int*)d_in[6];
    const int*   item_emb_idxes = (const int*)d_in[7];
    const int*   sess_rows      = (const int*)d_in[8];
    const int*   sess_cols      = (const int*)d_in[9];
    const int*   A_rows         = (const int*)d_in[10];
    const int*   A_cols         = (const int*)d_in[11];
    float* out = (float*)d_out;

    // -------- workspace layout (bytes), ~90 MB --------
    char* base = (char*)d_ws;
    ushort*   xw    = (ushort*)(base + 0);            // [N_TOTAL,128] bf16, 25.6MB
    ushort*   h1    = (ushort*)(base + 25600000L);    // [N_TOTAL,128] bf16, 25.6MB
    int2*     edgA  = (int2*)  (base + 51200000L);    // NB_A x STRIDE_A x 8B = 32.0MB
    int2*     edgS  = (int2*)  (base + 83210240L);    // NB_S x STRIDE_S x 8B = 6.4MB
    ushort*   Wt    = (ushort*)(base + 89616384L);    // 128x128 bf16, 32KB
    // zeroed-together region: bm | tailS | tailA
    unsigned* bm    = (unsigned*)(base + 89649152L);  // 3136 words
    int*      tailS = (int*)   (base + 89661696L);    // NB_S
    int*      tailA = (int*)   (base + 89664824L);    // NB_A

    ushort* xw_item = xw + (long)N_SESS * EMB;  // item half of xw

    // ---- zero bm + tails in one memset ----
    hipMemsetAsync(bm, 0, 89671076L - 89649152L, stream);
    // ---- PREP: mark needed h1 rows + convW ----
    k_prep<<<MARK_BLKS + 64, 256, 0, stream>>>(batch_idxes, item_idxes, bm, W, Wt);
    // ---- BUILD: strided placement (S, A-filtered) + fused-gather xw GEMM ----
    k_build<<<NBLK_S + NBLK_A + XW_BLKS, 256, 0, stream>>>(
        sess_rows, sess_cols, sess_vals, tailS, edgS,
        A_rows, A_cols, A_vals, tailA, edgA, bm,
        emb_table, item_emb_idxes, Wt, xw_item);
    // ---- spmm1 (reordered): xw[0:N_SESS] = S @ xw_item ----
    k_spmm_sorted<<<NB_S, 512, 0, stream>>>(tailS, edgS, STRIDE_S, xw_item, xw,
                                            nullptr, N_SESS, nullptr);
    // ---- spmm2 + fused bias -> h1 (only needed rows written) ----
    k_spmm_sorted<<<NB_A, 512, 0, stream>>>(tailA, edgA, STRIDE_A, xw, h1,
                                            b, N_TOTAL, bm);
    // ---- score (1D grid, XCD-swizzled, inline hb/hi gather, float4 NT stores) ----
    k_score_mfma<<<SB_TOT, 512, 0, stream>>>(h1, batch_idxes, item_idxes, out);
}

// Round 13
// 354.543 us; speedup vs baseline: 1.0791x; 1.0565x over previous
//
#include <hip/hip_runtime.h>

#define EMB 128
#define N_ITEMS 50000
#define N_SESS 50000
#define N_TOTAL 100000
#define NNZ_S 500000
#define NNZ_A 3200000
#define BATCH 2048
#define N_SCORE 50000

#define RPB 64                                 // rows per bucket
#define NB_A ((N_TOTAL + RPB - 1) / RPB)       // 1563
#define NB_S ((N_SESS + RPB - 1) / RPB)        // 782
#define NBMAX 1600
#define EPT 8
#define EPB (256 * EPT)                        // 2048 edges per build block
#define NBLK_S ((NNZ_S + EPB - 1) / EPB)       // 245
#define NBLK_A ((NNZ_A + EPB - 1) / EPB)       // 1563
#define XW_BLKS ((N_ITEMS + 127) / 128)        // 391
#define CHUNK 4096                             // edges staged per sort pass

#define STRIDE_S 1024                          // slots per S bucket (mean 640, sd 25)
#define STRIDE_A 2560                          // slots per A bucket (mean 2048, sd 45; filtered ~41%)

#define MARK_BLKS ((BATCH + N_SCORE + 255) / 256)  // 204

#define SB_X ((N_SCORE + 127) / 128)           // 391
#define SB_Y (BATCH / 256)                     // 8
#define SB_TOT (SB_X * SB_Y)                   // 3128 = 8 * 391

typedef __attribute__((ext_vector_type(8))) short bf16x8;
typedef __attribute__((ext_vector_type(4))) float f32x4;

__device__ inline ushort f2bf(float f) {
    unsigned u = __float_as_uint(f);
    unsigned r = (u + 0x7fff + ((u >> 16) & 1)) >> 16;
    return (ushort)r;
}
__device__ inline float bflo(unsigned u) { return __uint_as_float(u << 16); }
__device__ inline float bfhi(unsigned u) { return __uint_as_float(u & 0xffff0000u); }

// ---------------- PREP: mark needed h1 rows + W transpose ----------------
__global__ __launch_bounds__(256) void k_prep(const int* __restrict__ bidx, const int* __restrict__ iidx,
                                              unsigned* __restrict__ bm,
                                              const float* __restrict__ W, ushort* __restrict__ Wt) {
    int blk = blockIdx.x;
    int tid = threadIdx.x;
    if (blk < MARK_BLKS) {
        int i = blk * 256 + tid;
        int r = -1;
        if (i < BATCH) r = bidx[i];
        else if (i < BATCH + N_SCORE) r = iidx[i - BATCH];
        if (r >= 0) atomicOr(&bm[r >> 5], 1u << (r & 31));
    } else {
        int i = (blk - MARK_BLKS) * 256 + tid;
        int n = i >> 7, k = i & 127;
        Wt[n * 128 + k] = f2bf(W[k * 128 + n]);
    }
}

// ---------------- BUILD: strided bucketed placement (S + A-filtered) + fused-gather xw GEMM ----------------
// edge packed: key = (row & 63) << 17 | col, val as int bits
__global__ __launch_bounds__(256) void k_build(const int* __restrict__ sRows, const int* __restrict__ sCols,
                                               const float* __restrict__ sVals, int* __restrict__ tailS,
                                               int2* __restrict__ edgS,
                                               const int* __restrict__ aRows, const int* __restrict__ aCols,
                                               const float* __restrict__ aVals, int* __restrict__ tailA,
                                               int2* __restrict__ edgA,
                                               const unsigned* __restrict__ bm,
                                               const float* __restrict__ emb,
                                               const int* __restrict__ emb_idx,
                                               const ushort* __restrict__ Wt,
                                               ushort* __restrict__ xw_item) {
    __shared__ int h[NBMAX];
    __shared__ int base_s[NBMAX];
    int blk = blockIdx.x;
    int tid = threadIdx.x;
    if (blk < NBLK_S + NBLK_A) {
        // ---- placement (strided regions, no scan needed) ----
        const int *rows, *cols;
        const float* vals;
        int* tail;
        int2* out;
        const unsigned* filt;
        int nnz, nb, stride;
        long b0;
        if (blk < NBLK_S) {
            rows = sRows; cols = sCols; vals = sVals; tail = tailS; out = edgS;
            filt = nullptr; nnz = NNZ_S; nb = NB_S; stride = STRIDE_S;
            b0 = (long)blk * EPB;
        } else {
            rows = aRows; cols = aCols; vals = aVals; tail = tailA; out = edgA;
            filt = bm; nnz = NNZ_A; nb = NB_A; stride = STRIDE_A;
            b0 = (long)(blk - NBLK_S) * EPB;
        }
        for (int i = tid; i < nb; i += 256) h[i] = 0;
        __syncthreads();
        int er[EPT], ec[EPT];
        float ev[EPT];
#pragma unroll
        for (int j = 0; j < EPT; ++j) {
            long e = b0 + j * 256 + tid;
            er[j] = -1;
            if (e < nnz) {
                int r = rows[e];
                if (!filt || ((filt[r >> 5] >> (r & 31)) & 1)) {
                    er[j] = r;
                    ec[j] = cols[e];
                    ev[j] = vals[e];
                    atomicAdd(&h[r >> 6], 1);
                }
            }
        }
        __syncthreads();
        for (int i = tid; i < nb; i += 256) {
            int v = h[i];
            if (v) base_s[i] = atomicAdd(&tail[i], v);
            h[i] = 0; // reuse as local cursor
        }
        __syncthreads();
#pragma unroll
        for (int j = 0; j < EPT; ++j) {
            if (er[j] >= 0) {
                int bk = er[j] >> 6;
                int loc = base_s[bk] + atomicAdd(&h[bk], 1);
                if (loc < stride) // paranoia clamp (prob ~0; keeps writes in-buffer)
                    out[(long)bk * stride + loc] = make_int2(((er[j] & 63) << 17) | ec[j],
                                                             __float_as_int(ev[j]));
            }
        }
    } else {
        // ---- xw_item = bf16(emb[emb_idx]) @ Wt^T via MFMA (fused gather, M = N_ITEMS) ----
        int bid = blk - NBLK_S - NBLK_A;
        int wid = tid >> 6;
        int lane = tid & 63;
        int wm = wid >> 1, wn = wid & 1;
        long m0 = (long)bid * 128 + wm * 64;
        int n0 = wn * 64;
        int r = lane & 15;
        int kg = lane >> 4;

        long arow[4];
#pragma unroll
        for (int mf = 0; mf < 4; ++mf) {
            long row = m0 + mf * 16 + r;
            if (row >= N_ITEMS) row = N_ITEMS - 1; // clamp, stores guarded
            arow[mf] = emb_idx[row];
        }

        f32x4 acc[4][4] = {};
#pragma unroll
        for (int ks = 0; ks < 4; ++ks) {
            bf16x8 a[4], b[4];
#pragma unroll
            for (int mf = 0; mf < 4; ++mf) {
                const float* p = emb + arow[mf] * EMB + ks * 32 + kg * 8;
                float4 lo = *(const float4*)p;
                float4 hi = *(const float4*)(p + 4);
                bf16x8 t;
                t[0] = (short)f2bf(lo.x); t[1] = (short)f2bf(lo.y);
                t[2] = (short)f2bf(lo.z); t[3] = (short)f2bf(lo.w);
                t[4] = (short)f2bf(hi.x); t[5] = (short)f2bf(hi.y);
                t[6] = (short)f2bf(hi.z); t[7] = (short)f2bf(hi.w);
                a[mf] = t;
            }
#pragma unroll
            for (int nf = 0; nf < 4; ++nf) {
                int row = n0 + nf * 16 + r;
                b[nf] = *(const bf16x8*)(Wt + (long)row * EMB + ks * 32 + kg * 8);
            }
#pragma unroll
            for (int mf = 0; mf < 4; ++mf)
#pragma unroll
                for (int nf = 0; nf < 4; ++nf)
                    acc[mf][nf] = __builtin_amdgcn_mfma_f32_16x16x32_bf16(a[mf], b[nf], acc[mf][nf], 0, 0, 0);
        }
#pragma unroll
        for (int mf = 0; mf < 4; ++mf) {
#pragma unroll
            for (int nf = 0; nf < 4; ++nf) {
                int col = n0 + nf * 16 + r;
#pragma unroll
                for (int j = 0; j < 4; ++j) {
                    long row = m0 + mf * 16 + kg * 4 + j;
                    if (row < N_ITEMS) xw_item[row * EMB + col] = f2bf(acc[mf][nf][j]);
                }
            }
        }
    }
}

// ---------------- sorted-bucket SpMM over strided edge regions ----------------
__global__ __launch_bounds__(512) void k_spmm_sorted(const int* __restrict__ tail,
                                                     const int2* __restrict__ edges, int stride,
                                                     const ushort* __restrict__ src,
                                                     ushort* __restrict__ dst,
                                                     const float* __restrict__ bias,
                                                     int nrows,
                                                     const unsigned* __restrict__ bm) {
    __shared__ int2 se[CHUNK];      // 32 KB sorted edge buffer
    __shared__ int hist[RPB], sofs[RPB], cur[RPB];
    int tid = threadIdx.x, lane = tid & 63, w = tid >> 6;
    int bk = blockIdx.x;
    long begin = (long)bk * stride;
    int cnt = tail[bk];
    if (cnt > stride) cnt = stride;
    long end = begin + cnt;

    float2 acc[8] = {};
    for (long cbase = begin; cbase < end; cbase += CHUNK) {
        int m = (int)(end - cbase);
        if (m > CHUNK) m = CHUNK;
        if (tid < RPB) hist[tid] = 0;
        __syncthreads();
        int2 er[CHUNK / 512];
#pragma unroll
        for (int j = 0; j < CHUNK / 512; ++j) {
            int idx = j * 512 + tid;
            if (idx < m) {
                er[j] = edges[cbase + idx];
                atomicAdd(&hist[er[j].x >> 17], 1);
            } else {
                er[j].x = -1;
            }
        }
        __syncthreads();
        if (w == 0) {
            int v = hist[lane];
            int x = v;
#pragma unroll
            for (int s = 1; s < 64; s <<= 1) {
                int t = __shfl_up(x, s, 64);
                if (lane >= s) x += t;
            }
            sofs[lane] = x - v;
            cur[lane] = x - v;
        }
        __syncthreads();
#pragma unroll
        for (int j = 0; j < CHUNK / 512; ++j) {
            if (er[j].x >= 0) {
                int lr = er[j].x >> 17;
                int p = atomicAdd(&cur[lr], 1);
                se[p] = er[j];
            }
        }
        __syncthreads();
#pragma unroll
        for (int i = 0; i < 8; ++i) {
            int lr = w * 8 + i;
            int e = sofs[lr];
            int s1 = e + hist[lr];
            for (; e + 4 <= s1; e += 4) {
                int2 e0 = se[e], e1 = se[e + 1], e2 = se[e + 2], e3 = se[e + 3];
                unsigned u0 = *(const unsigned*)(src + (long)(e0.x & 0x1FFFF) * EMB + lane * 2);
                unsigned u1 = *(const unsigned*)(src + (long)(e1.x & 0x1FFFF) * EMB + lane * 2);
                unsigned u2 = *(const unsigned*)(src + (long)(e2.x & 0x1FFFF) * EMB + lane * 2);
                unsigned u3 = *(const unsigned*)(src + (long)(e3.x & 0x1FFFF) * EMB + lane * 2);
                float v0 = __int_as_float(e0.y), v1 = __int_as_float(e1.y);
                float v2 = __int_as_float(e2.y), v3 = __int_as_float(e3.y);
                acc[i].x += v0 * bflo(u0) + v1 * bflo(u1) + v2 * bflo(u2) + v3 * bflo(u3);
                acc[i].y += v0 * bfhi(u0) + v1 * bfhi(u1) + v2 * bfhi(u2) + v3 * bfhi(u3);
            }
            for (; e < s1; ++e) {
                int2 e0 = se[e];
                unsigned u0 = *(const unsigned*)(src + (long)(e0.x & 0x1FFFF) * EMB + lane * 2);
                float v0 = __int_as_float(e0.y);
                acc[i].x += v0 * bflo(u0);
                acc[i].y += v0 * bfhi(u0);
            }
        }
        __syncthreads();
    }
#pragma unroll
    for (int i = 0; i < 8; ++i) {
        int r = bk * RPB + w * 8 + i;
        if (r < nrows && (!bm || ((bm[r >> 5] >> (r & 31)) & 1))) {
            float a = acc[i].x, c = acc[i].y;
            if (bias) {
                a += bias[lane * 2];
                c += bias[lane * 2 + 1];
            }
            unsigned o = (unsigned)f2bf(a) | ((unsigned)f2bf(c) << 16);
            *((unsigned*)(dst + (long)r * EMB) + lane) = o;
        }
    }
}

// ---------------- out[2048, 50000] = h1[bidx] @ h1[iidx]^T via MFMA (inline gather) ----------------
// 512 threads, 256x128 tile (8 waves as 4m x 2n), 1D grid, col-major + chunked XCD swizzle.
__global__ __launch_bounds__(512) void k_score_mfma(const ushort* __restrict__ H,
                                                    const int* __restrict__ bidx,
                                                    const int* __restrict__ iidx,
                                                    float* __restrict__ C) {
    const int q = SB_TOT / 8; // 391, exact
    int bid = blockIdx.x;
    int nb = (bid % 8) * q + bid / 8;   // bijective chunked swizzle
    int bx = nb / SB_Y;                 // consecutive nb share bx (same hi slice)
    int by = nb % SB_Y;

    int wid = threadIdx.x >> 6;
    int lane = threadIdx.x & 63;
    int wm = wid >> 1, wn = wid & 1;    // wm 0..3, wn 0..1
    long m0 = (long)by * 256 + wm * 64;
    long n0 = (long)bx * 128 + wn * 64;
    int r = lane & 15;
    int kg = lane >> 4;

    long arow[4], brow[4];
#pragma unroll
    for (int mf = 0; mf < 4; ++mf) arow[mf] = bidx[m0 + mf * 16 + r];
#pragma unroll
    for (int nf = 0; nf < 4; ++nf) {
        long row = n0 + nf * 16 + r;
        if (row >= N_SCORE) row = N_SCORE - 1; // clamp: safe load, stores guarded
        brow[nf] = iidx[row];
    }

    f32x4 acc[4][4] = {};
#pragma unroll
    for (int ks = 0; ks < 4; ++ks) {
        bf16x8 a[4], b[4];
#pragma unroll
        for (int mf = 0; mf < 4; ++mf)
            a[mf] = *(const bf16x8*)(H + arow[mf] * EMB + ks * 32 + kg * 8);
#pragma unroll
        for (int nf = 0; nf < 4; ++nf)
            b[nf] = *(const bf16x8*)(H + brow[nf] * EMB + ks * 32 + kg * 8);
#pragma unroll
        for (int mf = 0; mf < 4; ++mf)
#pragma unroll
            for (int nf = 0; nf < 4; ++nf)
                acc[mf][nf] = __builtin_amdgcn_mfma_f32_16x16x32_bf16(a[mf], b[nf], acc[mf][nf], 0, 0, 0);
    }
#pragma unroll
    for (int mf = 0; mf < 4; ++mf) {
#pragma unroll
        for (int nf = 0; nf < 4; ++nf) {
            long col = n0 + nf * 16 + r;
            if (col < N_SCORE) {
#pragma unroll
                for (int j = 0; j < 4; ++j) {
                    long row = m0 + mf * 16 + kg * 4 + j;
                    __builtin_nontemporal_store(acc[mf][nf][j], &C[row * N_SCORE + col]);
                }
            }
        }
    }
}

extern "C" void kernel_launch(void* const* d_in, const int* in_sizes, int n_in,
                              void* d_out, int out_size, void* d_ws, size_t ws_size,
                              hipStream_t stream) {
    const float* emb_table      = (const float*)d_in[0];
    const float* W              = (const float*)d_in[1];
    const float* b              = (const float*)d_in[2];
    const float* sess_vals      = (const float*)d_in[3];
    const float* A_vals         = (const float*)d_in[4];
    const int*   batch_idxes    = (const int*)d_in[5];
    const int*   item_idxes     = (const int*)d_in[6];
    const int*   item_emb_idxes = (const int*)d_in[7];
    const int*   sess_rows      = (const int*)d_in[8];
    const int*   sess_cols      = (const int*)d_in[9];
    const int*   A_rows         = (const int*)d_in[10];
    const int*   A_cols         = (const int*)d_in[11];
    float* out = (float*)d_out;

    // -------- workspace layout (bytes), ~90 MB --------
    char* base = (char*)d_ws;
    ushort*   xw    = (ushort*)(base + 0);            // [N_TOTAL,128] bf16, 25.6MB
    ushort*   h1    = (ushort*)(base + 25600000L);    // [N_TOTAL,128] bf16, 25.6MB
    int2*     edgA  = (int2*)  (base + 51200000L);    // NB_A x STRIDE_A x 8B = 32.0MB
    int2*     edgS  = (int2*)  (base + 83210240L);    // NB_S x STRIDE_S x 8B = 6.4MB
    ushort*   Wt    = (ushort*)(base + 89616384L);    // 128x128 bf16, 32KB
    // zeroed-together region: bm | tailS | tailA
    unsigned* bm    = (unsigned*)(base + 89649152L);  // 3136 words
    int*      tailS = (int*)   (base + 89661696L);    // NB_S
    int*      tailA = (int*)   (base + 89664824L);    // NB_A

    ushort* xw_item = xw + (long)N_SESS * EMB;  // item half of xw

    // ---- zero bm + tails in one memset ----
    hipMemsetAsync(bm, 0, 89671076L - 89649152L, stream);
    // ---- PREP: mark needed h1 rows + convW ----
    k_prep<<<MARK_BLKS + 64, 256, 0, stream>>>(batch_idxes, item_idxes, bm, W, Wt);
    // ---- BUILD: strided placement (S, A-filtered) + fused-gather xw GEMM ----
    k_build<<<NBLK_S + NBLK_A + XW_BLKS, 256, 0, stream>>>(
        sess_rows, sess_cols, sess_vals, tailS, edgS,
        A_rows, A_cols, A_vals, tailA, edgA, bm,
        emb_table, item_emb_idxes, Wt, xw_item);
    // ---- spmm1 (reordered): xw[0:N_SESS] = S @ xw_item ----
    k_spmm_sorted<<<NB_S, 512, 0, stream>>>(tailS, edgS, STRIDE_S, xw_item, xw,
                                            nullptr, N_SESS, nullptr);
    // ---- spmm2 + fused bias -> h1 (only needed rows written) ----
    k_spmm_sorted<<<NB_A, 512, 0, stream>>>(tailA, edgA, STRIDE_A, xw, h1,
                                            b, N_TOTAL, bm);
    // ---- score (1D grid, XCD-swizzled, inline hb/hi gather, 256x128 tiles) ----
    k_score_mfma<<<SB_TOT, 512, 0, stream>>>(h1, batch_idxes, item_idxes, out);
}